// Round 1
// baseline (302.941 us; speedup 1.0000x reference)
//
#include <hip/hip_runtime.h>

// ---------------------------------------------------------------------------
// BCNet: v_=relu(v@Wv^T+bv); q_=relu(q@Wq^T+bq); out[b,h,v,q]=sum_k h[h,k]*v_*q_ + hbias[h]
// Shapes: B=32, NV=512, NQ=128, V_DIM=2048, Q_DIM=1024, HK=1536, H_OUT=8
// ---------------------------------------------------------------------------

typedef _Float16 h8 __attribute__((ext_vector_type(8)));
typedef float f32x4 __attribute__((ext_vector_type(4)));

#define B_   32
#define NV_  512
#define NQ_  128
#define VD_  2048
#define QD_  1024
#define HK_  1536
#define HO_  8

__device__ __forceinline__ void gload_lds16(const void* g, void* l) {
  __builtin_amdgcn_global_load_lds(
      (const __attribute__((address_space(1))) void*)g,
      (__attribute__((address_space(3))) void*)l, 16, 0, 0);
}

// ---------------------------------------------------------------------------
// f32 -> f16 conversion, 8 elements/thread (32B in, 16B out)
// ---------------------------------------------------------------------------
__global__ __launch_bounds__(256) void cvt_f32_f16(const float* __restrict__ in,
                                                   _Float16* __restrict__ out,
                                                   int n8) {
  int i = blockIdx.x * blockDim.x + threadIdx.x;
  if (i >= n8) return;
  const float4* p = (const float4*)in;
  float4 a = p[i * 2];
  float4 b = p[i * 2 + 1];
  h8 o;
  o[0] = (_Float16)a.x; o[1] = (_Float16)a.y; o[2] = (_Float16)a.z; o[3] = (_Float16)a.w;
  o[4] = (_Float16)b.x; o[5] = (_Float16)b.y; o[6] = (_Float16)b.z; o[7] = (_Float16)b.w;
  ((h8*)out)[i] = o;
}

// ---------------------------------------------------------------------------
// GEMM: out[m][n] = relu( sum_k A[m][k]*Bw[n][k] + bias[n] ), f16 in, f16 out
// Tile 128x128, BK=64, 4 waves (2x2), 4x4 16x16x32 MFMA frags per wave.
// Grid: (M/128, N/128). A: M x KTOT (K-major). Bw: N x KTOT (K-major).
// ---------------------------------------------------------------------------
template <int KTOT>
__global__ __launch_bounds__(256) void gemm_relu_f16(
    const _Float16* __restrict__ A, const _Float16* __restrict__ Bw,
    const float* __restrict__ bias, _Float16* __restrict__ out, int N) {
  __shared__ __align__(16) _Float16 As[128 * 64];
  __shared__ __align__(16) _Float16 Bs[128 * 64];

  const int lane = threadIdx.x & 63;
  const int wave = threadIdx.x >> 6;
  const int wm = wave >> 1, wn = wave & 1;
  const int brow = blockIdx.x * 128;
  const int bcol = blockIdx.y * 128;
  const int sr = lane >> 3;        // 0..7 : row within 8-row chunk
  const int sk = (lane & 7) * 8;   // 0..56: k element offset

  f32x4 acc[4][4] = {};

  for (int kt = 0; kt < KTOT / 64; ++kt) {
    __syncthreads();  // previous compute done before overwriting LDS
#pragma unroll
    for (int i = 0; i < 4; ++i) {
      const int c = wave * 4 + i;          // chunk 0..15, 8 rows each
      const int row = c * 8 + sr;
      gload_lds16(A + (size_t)(brow + row) * KTOT + kt * 64 + sk,
                  &As[c * 512 + lane * 8]);
      gload_lds16(Bw + (size_t)(bcol + row) * KTOT + kt * 64 + sk,
                  &Bs[c * 512 + lane * 8]);
    }
    __syncthreads();  // staged data visible
#pragma unroll
    for (int kk = 0; kk < 2; ++kk) {
      h8 af[4], bf[4];
#pragma unroll
      for (int m = 0; m < 4; ++m)
        af[m] = *(const h8*)&As[(wm * 64 + m * 16 + (lane & 15)) * 64 + kk * 32 + (lane >> 4) * 8];
#pragma unroll
      for (int n = 0; n < 4; ++n)
        bf[n] = *(const h8*)&Bs[(wn * 64 + n * 16 + (lane & 15)) * 64 + kk * 32 + (lane >> 4) * 8];
#pragma unroll
      for (int m = 0; m < 4; ++m)
#pragma unroll
        for (int n = 0; n < 4; ++n)
          acc[m][n] = __builtin_amdgcn_mfma_f32_16x16x32_f16(af[m], bf[n], acc[m][n], 0, 0, 0);
    }
  }

#pragma unroll
  for (int m = 0; m < 4; ++m) {
#pragma unroll
    for (int n = 0; n < 4; ++n) {
      const int col = bcol + wn * 64 + n * 16 + (lane & 15);
      const float bb = bias[col];
#pragma unroll
      for (int r = 0; r < 4; ++r) {
        const int row = brow + wm * 64 + m * 16 + (lane >> 4) * 4 + r;
        float val = acc[m][n][r] + bb;
        val = val > 0.f ? val : 0.f;
        out[(size_t)row * N + col] = (_Float16)val;
      }
    }
  }
}

// ---------------------------------------------------------------------------
// Bilinear: out[b,h,v,q] = sum_k vh[b,v,k] * (h16[h,k]*qh[b,q,k]) + hbias[h]
// One block per (m-tile, h, b). A-tile = vh rows (global_load_lds);
// B-tile = qh rows scaled by h16 row during reg staging (v_pk_mul_f16).
// ---------------------------------------------------------------------------
__global__ __launch_bounds__(256) void bilinear_f16(
    const _Float16* __restrict__ vh, const _Float16* __restrict__ qh,
    const _Float16* __restrict__ h16, const float* __restrict__ hbias,
    float* __restrict__ out) {
  __shared__ __align__(16) _Float16 As[128 * 64];
  __shared__ __align__(16) _Float16 Bs[128 * 64];

  const int lane = threadIdx.x & 63;
  const int wave = threadIdx.x >> 6;
  const int wm = wave >> 1, wn = wave & 1;
  const int t = threadIdx.x;
  const int mt = blockIdx.x;  // 0..3  (512/128 v-row tiles)
  const int h = blockIdx.y;   // 0..7
  const int b = blockIdx.z;   // 0..31

  const _Float16* Ab = vh + ((size_t)b * NV_ + mt * 128) * HK_;
  const _Float16* Qb = qh + (size_t)b * NQ_ * HK_;
  const _Float16* Hb = h16 + h * HK_;

  const int sr = lane >> 3;
  const int sk = (lane & 7) * 8;

  f32x4 acc[4][4] = {};

  for (int kt = 0; kt < HK_ / 64; ++kt) {
    __syncthreads();
    // A tile (v_) via direct-to-LDS
#pragma unroll
    for (int i = 0; i < 4; ++i) {
      const int c = wave * 4 + i;
      gload_lds16(Ab + (size_t)(c * 8 + sr) * HK_ + kt * 64 + sk,
                  &As[c * 512 + lane * 8]);
    }
    // B tile (q_ scaled by h row) via registers + packed f16 mul
    const h8 hv = *(const h8*)&Hb[kt * 64 + (t & 7) * 8];
#pragma unroll
    for (int r = 0; r < 4; ++r) {
      const int slot = r * 256 + t;     // 0..1023 16B slots
      const int row = slot >> 3;        // q index 0..127
      const h8 qv = *(const h8*)&Qb[(size_t)row * HK_ + kt * 64 + (t & 7) * 8];
      h8 o = qv * hv;
      *(h8*)&Bs[slot * 8] = o;
    }
    __syncthreads();
#pragma unroll
    for (int kk = 0; kk < 2; ++kk) {
      h8 af[4], bf[4];
#pragma unroll
      for (int m = 0; m < 4; ++m)
        af[m] = *(const h8*)&As[(wm * 64 + m * 16 + (lane & 15)) * 64 + kk * 32 + (lane >> 4) * 8];
#pragma unroll
      for (int n = 0; n < 4; ++n)
        bf[n] = *(const h8*)&Bs[(wn * 64 + n * 16 + (lane & 15)) * 64 + kk * 32 + (lane >> 4) * 8];
#pragma unroll
      for (int m = 0; m < 4; ++m)
#pragma unroll
        for (int n = 0; n < 4; ++n)
          acc[m][n] = __builtin_amdgcn_mfma_f32_16x16x32_f16(af[m], bf[n], acc[m][n], 0, 0, 0);
    }
  }

  const float bb = hbias[h];
  float* O = out + (((size_t)b * HO_ + h) * NV_ + (size_t)mt * 128) * NQ_;
#pragma unroll
  for (int m = 0; m < 4; ++m)
#pragma unroll
    for (int n = 0; n < 4; ++n)
#pragma unroll
      for (int r = 0; r < 4; ++r) {
        const int row = wm * 64 + m * 16 + (lane >> 4) * 4 + r;
        const int col = wn * 64 + n * 16 + (lane & 15);
        O[(size_t)row * NQ_ + col] = acc[m][n][r] + bb;
      }
}

// ---------------------------------------------------------------------------
// Workspace layout (bytes):
//   v16  @ 0          : 33,554,432 f16 = 67,108,864
//   q16  @ 67108864   :  4,194,304 f16 =  8,388,608
//   Wv16 @ 75497472   :  3,145,728 f16 =  6,291,456
//   Wq16 @ 81788928   :  1,572,864 f16 =  3,145,728
//   vh   @ 84934656   : 25,165,824 f16 = 50,331,648
//   qh   @ 135266304  :  6,291,456 f16 = 12,582,912
//   h16  @ 147849216  :     12,288 f16 =     24,576
//   total = 147,873,792
// ---------------------------------------------------------------------------
extern "C" void kernel_launch(void* const* d_in, const int* in_sizes, int n_in,
                              void* d_out, int out_size, void* d_ws,
                              size_t ws_size, hipStream_t stream) {
  const float* v = (const float*)d_in[0];
  const float* q = (const float*)d_in[1];
  const float* Wv = (const float*)d_in[2];
  const float* bv = (const float*)d_in[3];
  const float* Wq = (const float*)d_in[4];
  const float* bq = (const float*)d_in[5];
  const float* hmat = (const float*)d_in[6];
  const float* hbias = (const float*)d_in[7];

  if (ws_size < 147873792u) return;  // insufficient scratch -> clean fail

  char* ws = (char*)d_ws;
  _Float16* v16 = (_Float16*)(ws);
  _Float16* q16 = (_Float16*)(ws + 67108864);
  _Float16* Wv16 = (_Float16*)(ws + 75497472);
  _Float16* Wq16 = (_Float16*)(ws + 81788928);
  _Float16* vh = (_Float16*)(ws + 84934656);
  _Float16* qh = (_Float16*)(ws + 135266304);
  _Float16* h16 = (_Float16*)(ws + 147849216);

  // conversions (all sizes divisible by 8)
  cvt_f32_f16<<<dim3((33554432 / 8 + 255) / 256), 256, 0, stream>>>(v, v16, 33554432 / 8);
  cvt_f32_f16<<<dim3((4194304 / 8 + 255) / 256), 256, 0, stream>>>(q, q16, 4194304 / 8);
  cvt_f32_f16<<<dim3((3145728 / 8 + 255) / 256), 256, 0, stream>>>(Wv, Wv16, 3145728 / 8);
  cvt_f32_f16<<<dim3((1572864 / 8 + 255) / 256), 256, 0, stream>>>(Wq, Wq16, 1572864 / 8);
  cvt_f32_f16<<<dim3((12288 / 8 + 255) / 256), 256, 0, stream>>>(hmat, h16, 12288 / 8);

  // v_ = relu(v @ Wv^T + bv): M=16384, N=1536, K=2048
  gemm_relu_f16<VD_><<<dim3(16384 / 128, HK_ / 128), 256, 0, stream>>>(v16, Wv16, bv, vh, HK_);
  // q_ = relu(q @ Wq^T + bq): M=4096, N=1536, K=1024
  gemm_relu_f16<QD_><<<dim3(4096 / 128, HK_ / 128), 256, 0, stream>>>(q16, Wq16, bq, qh, HK_);

  // logits
  bilinear_f16<<<dim3(NV_ / 128, HO_, B_), 256, 0, stream>>>(vh, qh, h16, hbias, (float*)d_out);
}